// Round 6
// baseline (121.822 us; speedup 1.0000x reference)
//
#include <hip/hip_runtime.h>
#include <cstdint>
#include <cmath>

#define DEV __device__ __forceinline__

typedef float v4f __attribute__((ext_vector_type(4)));
typedef short v8s __attribute__((ext_vector_type(8)));

// Problem constants
// x: [8,256,48,48] f32; weight: [256,256,3,3]; off_w: [18,256,3,3]; off_b:[18];
// mask_w: [9,256,3,3]; mask_b:[9]; out: [8,256,48,48] f32
static constexpr int HW    = 48 * 48;        // 2304
static constexpr int NPOS  = 8 * HW;         // 18432

DEV float bf2f(unsigned short u) {
  unsigned int v = ((unsigned int)u) << 16;
  float f; __builtin_memcpy(&f, &v, 4); return f;
}
DEV unsigned short f2bf(float f) {
  unsigned int u; __builtin_memcpy(&u, &f, 4);
  unsigned int r = (u + 0x7fffu + ((u >> 16) & 1u)) >> 16;
  return (unsigned short)r;
}

DEV void gload16(const void* g, void* l) {
  __builtin_amdgcn_global_load_lds(
      (const __attribute__((address_space(1))) unsigned int*)g,
      (__attribute__((address_space(3))) unsigned int*)l, 16, 0, 0);
}

// ---- prep: offset/mask weights -> Wc2[32][k=t*256+c] bf16 (rows 27..31 = 0);
//      also zero the 512B zero-page used for OOB im2col rows.
__global__ void k_wc(const float* __restrict__ off_w, const float* __restrict__ mask_w,
                     unsigned short* __restrict__ Wc2, unsigned short* __restrict__ zp) {
  int i = blockIdx.x * 256 + threadIdx.x;     // 32*2304 = 73728 (288 blocks)
  if (i < 256) zp[i] = 0;
  int o = i / 2304, col = i % 2304;
  int t = col >> 8, c = col & 255;
  float v = 0.f;
  if (o < 18)      v = off_w[(o * 256 + c) * 9 + t];
  else if (o < 27) v = mask_w[((o - 18) * 256 + c) * 9 + t];
  Wc2[i] = f2bf(v);
}

// ---------------- prep: weight OIHW f32 -> wG[co][k*256+c] bf16 --------------
__global__ void k_wg(const float* __restrict__ weight, unsigned short* __restrict__ wG) {
  __shared__ float wrow[2304];
  int co = blockIdx.x;
  const float* wsrc = weight + (size_t)co * 2304;
  for (int i = threadIdx.x; i < 2304; i += 256) wrow[i] = wsrc[i];
  __syncthreads();
  unsigned short* dst = wG + (size_t)co * 2304;
  #pragma unroll
  for (int k = 0; k < 9; k++)
    dst[k * 256 + threadIdx.x] = f2bf(wrow[threadIdx.x * 9 + k]);
}

// ---------------- prep: x NCHW f32 -> xT [b][hw][c] bf16 ---------------------
__global__ void k_xt(const float* __restrict__ x, unsigned short* __restrict__ xT) {
  __shared__ float tile[64][65];
  int bid = blockIdx.x;                 // b*144 + hwt*4 + ct
  int ct = bid & 3; int hwt = (bid >> 2) % 36; int b = bid / 144;
  int c0 = ct * 64, hw0 = hwt * 64;
  int tl = threadIdx.x & 63, tr = threadIdx.x >> 6;
  const float* xb = x + (size_t)(b * 256 + c0) * 2304 + hw0;
  #pragma unroll
  for (int r = 0; r < 16; r++) {
    int cr = tr + r * 4;
    tile[cr][tl] = xb[(size_t)cr * 2304 + tl];
  }
  __syncthreads();
  unsigned short* xo = xT + ((size_t)b * 2304 + hw0) * 256 + c0;
  #pragma unroll
  for (int r = 0; r < 16; r++) {
    int hr = tr + r * 4;
    xo[(size_t)hr * 256 + tl] = f2bf(tile[tl][hr]);
  }
}

// ---------------- offset/mask conv as MFMA GEMM ------------------------------
// S[32][NPOS] = Wc2[32][2304] * im2col(xT)[2304][NPOS], split-K by tap triple.
// grid (288, 3): BN=64, per chunk K=768 (3 taps x 256 ch), BK=64.
// parS layout: [kc][32][NPOS] fp32.
__global__ __launch_bounds__(256) void k_cg(const unsigned short* __restrict__ Wc2,
                                            const unsigned short* __restrict__ xT,
                                            const unsigned short* __restrict__ zp,
                                            float* __restrict__ parS) {
  __shared__ unsigned short ldsA[32 * 64];
  __shared__ unsigned short ldsB[64 * 64];
  int nt = blockIdx.x, kc = blockIdx.y;
  int n0 = nt * 64;
  int b = n0 / 2304, hw0 = n0 % 2304;         // BN=64 divides 2304: one image
  int tid = threadIdx.x, lane = tid & 63, wid = tid >> 6;
  int r = lane & 15, q = lane >> 4;
  int row0 = tid >> 3;                        // staging row (0..31)
  int sslot = (tid & 7) ^ (row0 & 7);         // pre-swizzled 16B slot

  int hwA = hw0 + row0,      hA = hwA / 48, wA = hwA % 48;   // B round 0 row
  int hwB = hw0 + row0 + 32, hB = hwB / 48, wB = hwB % 48;   // B round 1 row

  v4f acc0 = (v4f){0.f, 0.f, 0.f, 0.f};
  v4f acc1 = (v4f){0.f, 0.f, 0.f, 0.f};

  #pragma unroll
  for (int tt = 0; tt < 3; tt++) {
    int t = kc * 3 + tt;
    int dy = kc - 1, dx = tt - 1;
    int yA = hA + dy, xA = wA + dx;
    int yB = hB + dy, xB = wB + dx;
    bool vA = ((unsigned)yA < 48u) && ((unsigned)xA < 48u);
    bool vB = ((unsigned)yB < 48u) && ((unsigned)xB < 48u);
    const unsigned short* baseA2 = Wc2 + (size_t)row0 * 2304 + t * 256 + sslot * 8;
    const unsigned short* base0 = vA ? xT + ((size_t)(b * 2304 + yA * 48 + xA) * 256 + sslot * 8)
                                     : zp + sslot * 8;
    const unsigned short* base1 = vB ? xT + ((size_t)(b * 2304 + yB * 48 + xB) * 256 + sslot * 8)
                                     : zp + sslot * 8;
    #pragma unroll
    for (int cq = 0; cq < 4; cq++) {
      int c0s = cq * 64;
      __syncthreads();                        // prev tile reads done
      gload16(baseA2 + c0s, ldsA + tid * 8);
      gload16(base0  + c0s, ldsB + tid * 8);
      gload16(base1  + c0s, ldsB + 2048 + tid * 8);
      __syncthreads();                        // drain vmcnt + barrier
      #pragma unroll
      for (int ki = 0; ki < 2; ki++) {
        int sl = ((ki * 4 + q) ^ (r & 7)) * 8;
        v8s a0 = *(const v8s*)&ldsA[r * 64 + sl];
        v8s a1 = *(const v8s*)&ldsA[(16 + r) * 64 + sl];
        v8s bb = *(const v8s*)&ldsB[(wid * 16 + r) * 64 + sl];
        acc0 = __builtin_amdgcn_mfma_f32_16x16x32_bf16(a0, bb, acc0, 0, 0, 0);
        acc1 = __builtin_amdgcn_mfma_f32_16x16x32_bf16(a1, bb, acc1, 0, 0, 0);
      }
    }
  }

  float* pp = parS + (size_t)kc * 32 * NPOS + n0;
  #pragma unroll
  for (int e = 0; e < 4; e++) {
    pp[(size_t)(q * 4 + e) * NPOS      + wid * 16 + r] = acc0[e];
    pp[(size_t)(16 + q * 4 + e) * NPOS + wid * 16 + r] = acc1[e];
  }
}

// ---------------- finalize: reduce 3 chunks, bias, sigmoid, coords -----------
// smp layout: [k][pos][{py,px,m}]
__global__ __launch_bounds__(256) void k_fin(const float* __restrict__ parS,
                                             const float* __restrict__ off_b,
                                             const float* __restrict__ mask_b,
                                             float* __restrict__ smp) {
  int k = blockIdx.x / 72;                    // 72 blocks per k (NPOS/256)
  int pos = (blockIdx.x % 72) * 256 + threadIdx.x;
  float s0 = 0.f, s1 = 0.f, s2 = 0.f;
  #pragma unroll
  for (int g = 0; g < 3; g++) {
    const float* pg = parS + (size_t)g * 32 * NPOS + pos;
    s0 += pg[(size_t)(2 * k)     * NPOS];
    s1 += pg[(size_t)(2 * k + 1) * NPOS];
    s2 += pg[(size_t)(18 + k)    * NPOS];
  }
  int hw = pos % 2304; int h = hw / 48, w = hw % 48;
  float m = 1.f / (1.f + expf(-(s2 + mask_b[k])));
  float* sp = smp + ((size_t)k * NPOS + pos) * 3;
  sp[0] = s0 + off_b[2 * k]     + (float)(k / 3) + (float)h - 1.f;
  sp[1] = s1 + off_b[2 * k + 1] + (float)(k % 3) + (float)w - 1.f;
  sp[2] = m;
}

// ---------------- zero the output (required: fused GEMM accumulates) ---------
__global__ __launch_bounds__(256) void k_zero(float* __restrict__ out) {
  int i = blockIdx.x * 256 + threadIdx.x;     // 1179648 float4 = 4608 blocks
  ((v4f*)out)[i] = (v4f){0.f, 0.f, 0.f, 0.f};
}

// ---------------- fused deformable-gather + GEMM (TLP version) ---------------
// C[co][n] += sum_{K-quarter} wG[co][K] * gather(xT,smp)[K][n]
// BM=256 (full M), BN=64, BK=64. Split-K 4-way by 64-channel quarter.
// 1152 blocks x 512 threads, 9 K-steps each. LDS 40960 B -> 4 blocks/CU;
// __launch_bounds__(512,8) keeps VGPR<=64 so 32 waves/CU fit. TLP (4 resident
// blocks) hides the per-step gather/barrier latency that R4/R5 could not.
__global__ __launch_bounds__(512, 8) void k_fg(const unsigned short* __restrict__ wG,
                                               const unsigned short* __restrict__ xT,
                                               const float* __restrict__ smp,
                                               float* __restrict__ out) {
  __shared__ unsigned short ldsA[256 * 64];   // 32 KB, [co][k] swizzled slots
  __shared__ unsigned short ldsB[64 * 64];    //  8 KB, [n][k]  swizzled slots
  // bijective XCD swizzle: each XCD -> 72 consecutive nt (2 images) x 2 kc
  int raw = blockIdx.x;                       // 1152 = 288 nt x 4 kc
  int xcd = raw & 7, idx = raw >> 3;          // idx 0..143
  int kc  = (xcd >> 2) * 2 + (idx / 72);      // 0..3
  int nt  = (xcd & 3) * 72 + (idx % 72);      // 0..287
  int n0 = nt * 64;
  int c0 = kc * 64;                           // channel quarter base
  int b = n0 / 2304, hw0 = n0 % 2304;         // 64 | 2304: single image
  int tid = threadIdx.x, lane = tid & 63, wid = tid >> 6;
  int wm = wid & 3, wn = wid >> 2;            // 4 m-waves x 2 n-waves
  int r = lane & 15, q = lane >> 4;
  int p = tid >> 3, j = tid & 7;              // gather: 8 threads per position
  int pos = b * 2304 + hw0 + p;
  const unsigned short* xb = xT + (size_t)b * 2304 * 256;
  int aslot = j ^ (p & 7);                    // pre-swizzled A source slot
  int cb = c0 + j * 8;

  v4f acc[4][2];
  #pragma unroll
  for (int i = 0; i < 4; i++)
    #pragma unroll
    for (int jj = 0; jj < 2; jj++) acc[i][jj] = (v4f){0.f, 0.f, 0.f, 0.f};

  for (int t = 0; t < 9; t++) {
    __syncthreads();                          // prev step's LDS reads done
    // ---- stage A: 256x64 via global_load_lds, pre-swizzled source
    #pragma unroll
    for (int rd = 0; rd < 4; rd++)
      gload16(wG + (size_t)(rd * 64 + p) * 2304 + t * 256 + c0 + aslot * 8,
              ldsA + rd * 4096 + tid * 8);
    // ---- per-position bilinear setup + corner loads
    const float* sp = smp + ((size_t)t * NPOS + pos) * 3;
    float py = sp[0], px = sp[1], m = sp[2];
    float y0f = floorf(py), x0f = floorf(px);
    float wy = py - y0f, wx = px - x0f;
    int y0 = (int)y0f, x0 = (int)x0f;
    bool vy0 = (y0 >= 0) && (y0 <= 47), vy1 = (y0 >= -1) && (y0 <= 46);
    bool vx0 = (x0 >= 0) && (x0 <= 47), vx1 = (x0 >= -1) && (x0 <= 46);
    int yc0 = min(max(y0, 0), 47), yc1 = min(max(y0 + 1, 0), 47);
    int xc0 = min(max(x0, 0), 47), xc1 = min(max(x0 + 1, 0), 47);
    float w00 = (1.f - wy) * (1.f - wx) * m * (float)(vy0 && vx0);
    float w01 = (1.f - wy) * wx         * m * (float)(vy0 && vx1);
    float w10 = wy         * (1.f - wx) * m * (float)(vy1 && vx0);
    float w11 = wy         * wx         * m * (float)(vy1 && vx1);
    v8s c00v = *(const v8s*)&xb[(yc0 * 48 + xc0) * 256 + cb];
    v8s c01v = *(const v8s*)&xb[(yc0 * 48 + xc1) * 256 + cb];
    v8s c10v = *(const v8s*)&xb[(yc1 * 48 + xc0) * 256 + cb];
    v8s c11v = *(const v8s*)&xb[(yc1 * 48 + xc1) * 256 + cb];
    // ---- gather B tile: 64 pos x 64 ch, swizzled ds_write
    unsigned short vb8[8];
    #pragma unroll
    for (int i = 0; i < 8; i++) {
      float v = w00 * bf2f((unsigned short)c00v[i])
              + w01 * bf2f((unsigned short)c01v[i])
              + w10 * bf2f((unsigned short)c10v[i])
              + w11 * bf2f((unsigned short)c11v[i]);
      vb8[i] = f2bf(v);
    }
    *(v8s*)&ldsB[p * 64 + (j ^ (p & 7)) * 8] = *(const v8s*)vb8;
    __syncthreads();                          // drains vmcnt + lgkm

    // ---- MFMA: 16 per wave per K-step
    __builtin_amdgcn_s_setprio(1);
    #pragma unroll
    for (int ki = 0; ki < 2; ki++) {
      v8s af[4], bfr[2];
      #pragma unroll
      for (int fm = 0; fm < 4; fm++) {
        int row = wm * 64 + fm * 16 + r;
        af[fm] = *(const v8s*)&ldsA[row * 64 + (((ki * 4 + q) ^ (r & 7)) * 8)];
      }
      #pragma unroll
      for (int fn = 0; fn < 2; fn++) {
        int row = wn * 32 + fn * 16 + r;
        bfr[fn] = *(const v8s*)&ldsB[row * 64 + (((ki * 4 + q) ^ (r & 7)) * 8)];
      }
      #pragma unroll
      for (int fm = 0; fm < 4; fm++)
        #pragma unroll
        for (int fn = 0; fn < 2; fn++)
          acc[fm][fn] = __builtin_amdgcn_mfma_f32_16x16x32_bf16(af[fm], bfr[fn], acc[fm][fn], 0, 0, 0);
    }
    __builtin_amdgcn_s_setprio(0);
  }

  // ---- epilogue: atomic accumulate (4 exact addends per element)
  float* op = out + (size_t)b * (256 * 2304) + hw0;
  #pragma unroll
  for (int fm = 0; fm < 4; fm++) {
    int co = wm * 64 + fm * 16 + q * 4;
    #pragma unroll
    for (int fn = 0; fn < 2; fn++) {
      int nn = wn * 32 + fn * 16 + r;
      #pragma unroll
      for (int e = 0; e < 4; e++)
        unsafeAtomicAdd(&op[(size_t)(co + e) * 2304 + nn], acc[fm][fn][e]);
    }
  }
}

extern "C" void kernel_launch(void* const* d_in, const int* in_sizes, int n_in,
                              void* d_out, int out_size, void* d_ws, size_t ws_size,
                              hipStream_t stream) {
  const float* x      = (const float*)d_in[0];
  const float* weight = (const float*)d_in[1];
  const float* off_w  = (const float*)d_in[2];
  const float* off_b  = (const float*)d_in[3];
  const float* mask_w = (const float*)d_in[4];
  const float* mask_b = (const float*)d_in[5];
  float* out = (float*)d_out;
  char* ws = (char*)d_ws;

  unsigned short* xT   = (unsigned short*)(ws);             //  9,437,184 B -> 9,437,184
  unsigned short* wG   = (unsigned short*)(ws + 9437184);   //  1,179,648 B -> 10,616,832
  unsigned short* Wc2  = (unsigned short*)(ws + 10616832);  //    147,456 B -> 10,764,288
  unsigned short* zp   = (unsigned short*)(ws + 10764288);  //        512 B -> 10,764,800
  float*          smp  = (float*)(ws + 10764800);           //  1,990,656 B -> 12,755,456
  float*          parS = (float*)(ws + 12755456);           //  7,077,888 B -> 19,833,344

  hipLaunchKernelGGL(k_zero,   dim3(4608),     dim3(256), 0, stream, out);
  hipLaunchKernelGGL(k_wc,     dim3(288),      dim3(256), 0, stream, off_w, mask_w, Wc2, zp);
  hipLaunchKernelGGL(k_wg,     dim3(256),      dim3(256), 0, stream, weight, wG);
  hipLaunchKernelGGL(k_xt,     dim3(1152),     dim3(256), 0, stream, x, xT);
  hipLaunchKernelGGL(k_cg,     dim3(288, 3),   dim3(256), 0, stream, Wc2, xT, zp, parS);
  hipLaunchKernelGGL(k_fin,    dim3(648),      dim3(256), 0, stream, parS, off_b, mask_b, smp);
  hipLaunchKernelGGL(k_fg,     dim3(1152),     dim3(512), 0, stream, wG, xT, smp, out);
}

// Round 7
// 121.476 us; speedup vs baseline: 1.0028x; 1.0028x over previous
//
#include <hip/hip_runtime.h>
#include <cstdint>
#include <cmath>

#define DEV __device__ __forceinline__

typedef float v4f __attribute__((ext_vector_type(4)));
typedef short v8s __attribute__((ext_vector_type(8)));

// Problem constants
// x: [8,256,48,48] f32; weight: [256,256,3,3]; off_w: [18,256,3,3]; off_b:[18];
// mask_w: [9,256,3,3]; mask_b:[9]; out: [8,256,48,48] f32
static constexpr int HW    = 48 * 48;        // 2304
static constexpr int NPOS  = 8 * HW;         // 18432

DEV float bf2f(unsigned short u) {
  unsigned int v = ((unsigned int)u) << 16;
  float f; __builtin_memcpy(&f, &v, 4); return f;
}
DEV unsigned short f2bf(float f) {
  unsigned int u; __builtin_memcpy(&u, &f, 4);
  unsigned int r = (u + 0x7fffu + ((u >> 16) & 1u)) >> 16;
  return (unsigned short)r;
}

DEV void gload16(const void* g, void* l) {
  __builtin_amdgcn_global_load_lds(
      (const __attribute__((address_space(1))) unsigned int*)g,
      (__attribute__((address_space(3))) unsigned int*)l, 16, 0, 0);
}

// ---- prep: offset/mask weights -> Wc2[32][k=t*256+c] bf16 (rows 27..31 = 0);
//      also zero the 512B zero-page used for OOB im2col rows.
__global__ void k_wc(const float* __restrict__ off_w, const float* __restrict__ mask_w,
                     unsigned short* __restrict__ Wc2, unsigned short* __restrict__ zp) {
  int i = blockIdx.x * 256 + threadIdx.x;     // 32*2304 = 73728 (288 blocks)
  if (i < 256) zp[i] = 0;
  int o = i / 2304, col = i % 2304;
  int t = col >> 8, c = col & 255;
  float v = 0.f;
  if (o < 18)      v = off_w[(o * 256 + c) * 9 + t];
  else if (o < 27) v = mask_w[((o - 18) * 256 + c) * 9 + t];
  Wc2[i] = f2bf(v);
}

// ---------------- prep: weight OIHW f32 -> wG[co][k*256+c] bf16 --------------
__global__ void k_wg(const float* __restrict__ weight, unsigned short* __restrict__ wG) {
  __shared__ float wrow[2304];
  int co = blockIdx.x;
  const float* wsrc = weight + (size_t)co * 2304;
  for (int i = threadIdx.x; i < 2304; i += 256) wrow[i] = wsrc[i];
  __syncthreads();
  unsigned short* dst = wG + (size_t)co * 2304;
  #pragma unroll
  for (int k = 0; k < 9; k++)
    dst[k * 256 + threadIdx.x] = f2bf(wrow[threadIdx.x * 9 + k]);
}

// ---------------- prep: x NCHW f32 -> xT [b][hw][c] bf16 ---------------------
__global__ void k_xt(const float* __restrict__ x, unsigned short* __restrict__ xT) {
  __shared__ float tile[64][65];
  int bid = blockIdx.x;                 // b*144 + hwt*4 + ct
  int ct = bid & 3; int hwt = (bid >> 2) % 36; int b = bid / 144;
  int c0 = ct * 64, hw0 = hwt * 64;
  int tl = threadIdx.x & 63, tr = threadIdx.x >> 6;
  const float* xb = x + (size_t)(b * 256 + c0) * 2304 + hw0;
  #pragma unroll
  for (int r = 0; r < 16; r++) {
    int cr = tr + r * 4;
    tile[cr][tl] = xb[(size_t)cr * 2304 + tl];
  }
  __syncthreads();
  unsigned short* xo = xT + ((size_t)b * 2304 + hw0) * 256 + c0;
  #pragma unroll
  for (int r = 0; r < 16; r++) {
    int hr = tr + r * 4;
    xo[(size_t)hr * 256 + tl] = f2bf(tile[tl][hr]);
  }
}

// ---------------- offset/mask conv as MFMA GEMM ------------------------------
// S[32][NPOS] = Wc2[32][2304] * im2col(xT)[2304][NPOS], split-K by tap triple.
// grid (288, 3): BN=64, per chunk K=768 (3 taps x 256 ch), BK=64.
// parS layout: [kc][32][NPOS] fp32.
__global__ __launch_bounds__(256) void k_cg(const unsigned short* __restrict__ Wc2,
                                            const unsigned short* __restrict__ xT,
                                            const unsigned short* __restrict__ zp,
                                            float* __restrict__ parS) {
  __shared__ unsigned short ldsA[32 * 64];
  __shared__ unsigned short ldsB[64 * 64];
  int nt = blockIdx.x, kc = blockIdx.y;
  int n0 = nt * 64;
  int b = n0 / 2304, hw0 = n0 % 2304;         // BN=64 divides 2304: one image
  int tid = threadIdx.x, lane = tid & 63, wid = tid >> 6;
  int r = lane & 15, q = lane >> 4;
  int row0 = tid >> 3;                        // staging row (0..31)
  int sslot = (tid & 7) ^ (row0 & 7);         // pre-swizzled 16B slot

  int hwA = hw0 + row0,      hA = hwA / 48, wA = hwA % 48;   // B round 0 row
  int hwB = hw0 + row0 + 32, hB = hwB / 48, wB = hwB % 48;   // B round 1 row

  v4f acc0 = (v4f){0.f, 0.f, 0.f, 0.f};
  v4f acc1 = (v4f){0.f, 0.f, 0.f, 0.f};

  #pragma unroll
  for (int tt = 0; tt < 3; tt++) {
    int t = kc * 3 + tt;
    int dy = kc - 1, dx = tt - 1;
    int yA = hA + dy, xA = wA + dx;
    int yB = hB + dy, xB = wB + dx;
    bool vA = ((unsigned)yA < 48u) && ((unsigned)xA < 48u);
    bool vB = ((unsigned)yB < 48u) && ((unsigned)xB < 48u);
    const unsigned short* baseA2 = Wc2 + (size_t)row0 * 2304 + t * 256 + sslot * 8;
    const unsigned short* base0 = vA ? xT + ((size_t)(b * 2304 + yA * 48 + xA) * 256 + sslot * 8)
                                     : zp + sslot * 8;
    const unsigned short* base1 = vB ? xT + ((size_t)(b * 2304 + yB * 48 + xB) * 256 + sslot * 8)
                                     : zp + sslot * 8;
    #pragma unroll
    for (int cq = 0; cq < 4; cq++) {
      int c0s = cq * 64;
      __syncthreads();                        // prev tile reads done
      gload16(baseA2 + c0s, ldsA + tid * 8);
      gload16(base0  + c0s, ldsB + tid * 8);
      gload16(base1  + c0s, ldsB + 2048 + tid * 8);
      __syncthreads();                        // drain vmcnt + barrier
      #pragma unroll
      for (int ki = 0; ki < 2; ki++) {
        int sl = ((ki * 4 + q) ^ (r & 7)) * 8;
        v8s a0 = *(const v8s*)&ldsA[r * 64 + sl];
        v8s a1 = *(const v8s*)&ldsA[(16 + r) * 64 + sl];
        v8s bb = *(const v8s*)&ldsB[(wid * 16 + r) * 64 + sl];
        acc0 = __builtin_amdgcn_mfma_f32_16x16x32_bf16(a0, bb, acc0, 0, 0, 0);
        acc1 = __builtin_amdgcn_mfma_f32_16x16x32_bf16(a1, bb, acc1, 0, 0, 0);
      }
    }
  }

  float* pp = parS + (size_t)kc * 32 * NPOS + n0;
  #pragma unroll
  for (int e = 0; e < 4; e++) {
    pp[(size_t)(q * 4 + e) * NPOS      + wid * 16 + r] = acc0[e];
    pp[(size_t)(16 + q * 4 + e) * NPOS + wid * 16 + r] = acc1[e];
  }
}

// ---------------- finalize: reduce 3 chunks, bias, sigmoid, coords -----------
// smp layout: [k][pos][{py,px,m}]
__global__ __launch_bounds__(256) void k_fin(const float* __restrict__ parS,
                                             const float* __restrict__ off_b,
                                             const float* __restrict__ mask_b,
                                             float* __restrict__ smp) {
  int k = blockIdx.x / 72;                    // 72 blocks per k (NPOS/256)
  int pos = (blockIdx.x % 72) * 256 + threadIdx.x;
  float s0 = 0.f, s1 = 0.f, s2 = 0.f;
  #pragma unroll
  for (int g = 0; g < 3; g++) {
    const float* pg = parS + (size_t)g * 32 * NPOS + pos;
    s0 += pg[(size_t)(2 * k)     * NPOS];
    s1 += pg[(size_t)(2 * k + 1) * NPOS];
    s2 += pg[(size_t)(18 + k)    * NPOS];
  }
  int hw = pos % 2304; int h = hw / 48, w = hw % 48;
  float m = 1.f / (1.f + expf(-(s2 + mask_b[k])));
  float* sp = smp + ((size_t)k * NPOS + pos) * 3;
  sp[0] = s0 + off_b[2 * k]     + (float)(k / 3) + (float)h - 1.f;
  sp[1] = s1 + off_b[2 * k + 1] + (float)(k % 3) + (float)w - 1.f;
  sp[2] = m;
}

// ---------------- zero the output (required: fused GEMM accumulates) ---------
__global__ __launch_bounds__(256) void k_zero(float* __restrict__ out) {
  int i = blockIdx.x * 256 + threadIdx.x;     // 1179648 float4 = 4608 blocks
  ((v4f*)out)[i] = (v4f){0.f, 0.f, 0.f, 0.f};
}

// ---------------- fused deformable-gather + GEMM (TLP, VGPR-freed) -----------
// C[co][n] += sum_{K-quarter} wG[co][K] * gather(xT,smp)[K][n]
// BM=256 (full M), BN=64, BK=64. Split-K 4-way by 64-channel quarter.
// 1152 blocks x 512 threads, 9 K-steps. LDS 40960 B (4 blocks/CU cap);
// __launch_bounds__(512,4): VGPR cap 128 so the 4 corner v8s stay in flight
// (R6's (512,8) squeezed VGPR to 32 and serialized the gather -> regression).
// smp prefetched one tap ahead: corner loads issue at barrier-exit.
__global__ __launch_bounds__(512, 4) void k_fg(const unsigned short* __restrict__ wG,
                                               const unsigned short* __restrict__ xT,
                                               const float* __restrict__ smp,
                                               float* __restrict__ out) {
  __shared__ unsigned short ldsA[256 * 64];   // 32 KB, [co][k] swizzled slots
  __shared__ unsigned short ldsB[64 * 64];    //  8 KB, [n][k]  swizzled slots
  // bijective XCD swizzle: each XCD -> 72 consecutive nt (2 images) x 2 kc
  int raw = blockIdx.x;                       // 1152 = 288 nt x 4 kc
  int xcd = raw & 7, idx = raw >> 3;          // idx 0..143
  int kc  = (xcd >> 2) * 2 + (idx / 72);      // 0..3
  int nt  = (xcd & 3) * 72 + (idx % 72);      // 0..287
  int n0 = nt * 64;
  int c0 = kc * 64;                           // channel quarter base
  int b = n0 / 2304, hw0 = n0 % 2304;         // 64 | 2304: single image
  int tid = threadIdx.x, lane = tid & 63, wid = tid >> 6;
  int wm = wid & 3, wn = wid >> 2;            // 4 m-waves x 2 n-waves
  int r = lane & 15, q = lane >> 4;
  int p = tid >> 3, j = tid & 7;              // gather: 8 threads per position
  int pos = b * 2304 + hw0 + p;
  const unsigned short* xb = xT + (size_t)b * 2304 * 256;
  int aslot = j ^ (p & 7);                    // pre-swizzled A source slot
  int cb = c0 + j * 8;

  v4f acc[4][2];
  #pragma unroll
  for (int i = 0; i < 4; i++)
    #pragma unroll
    for (int jj = 0; jj < 2; jj++) acc[i][jj] = (v4f){0.f, 0.f, 0.f, 0.f};

  // prefetch smp for tap 0
  float smy, smx, smm;
  {
    const float* sp0 = smp + (size_t)pos * 3; // t=0
    smy = sp0[0]; smx = sp0[1]; smm = sp0[2];
  }

  for (int t = 0; t < 9; t++) {
    __syncthreads();                          // prev step's LDS reads done
    // ---- corner loads first (smp already in regs): longest-latency chain
    float y0f = floorf(smy), x0f = floorf(smx);
    float wy = smy - y0f, wx = smx - x0f;
    int y0 = (int)y0f, x0 = (int)x0f;
    bool vy0 = (y0 >= 0) && (y0 <= 47), vy1 = (y0 >= -1) && (y0 <= 46);
    bool vx0 = (x0 >= 0) && (x0 <= 47), vx1 = (x0 >= -1) && (x0 <= 46);
    int yc0 = min(max(y0, 0), 47), yc1 = min(max(y0 + 1, 0), 47);
    int xc0 = min(max(x0, 0), 47), xc1 = min(max(x0 + 1, 0), 47);
    float w00 = (1.f - wy) * (1.f - wx) * smm * (float)(vy0 && vx0);
    float w01 = (1.f - wy) * wx         * smm * (float)(vy0 && vx1);
    float w10 = wy         * (1.f - wx) * smm * (float)(vy1 && vx0);
    float w11 = wy         * wx         * smm * (float)(vy1 && vx1);
    v8s c00v = *(const v8s*)&xb[(yc0 * 48 + xc0) * 256 + cb];
    v8s c01v = *(const v8s*)&xb[(yc0 * 48 + xc1) * 256 + cb];
    v8s c10v = *(const v8s*)&xb[(yc1 * 48 + xc0) * 256 + cb];
    v8s c11v = *(const v8s*)&xb[(yc1 * 48 + xc1) * 256 + cb];
    // ---- stage A: 256x64 via global_load_lds, pre-swizzled source
    #pragma unroll
    for (int rd = 0; rd < 4; rd++)
      gload16(wG + (size_t)(rd * 64 + p) * 2304 + t * 256 + c0 + aslot * 8,
              ldsA + rd * 4096 + tid * 8);
    // ---- prefetch smp for next tap (independent, overlaps corner latency)
    if (t + 1 < 9) {
      const float* spn = smp + ((size_t)(t + 1) * NPOS + pos) * 3;
      smy = spn[0]; smx = spn[1]; smm = spn[2];
    }
    // ---- gather B tile: 64 pos x 64 ch, swizzled ds_write
    unsigned short vb8[8];
    #pragma unroll
    for (int i = 0; i < 8; i++) {
      float v = w00 * bf2f((unsigned short)c00v[i])
              + w01 * bf2f((unsigned short)c01v[i])
              + w10 * bf2f((unsigned short)c10v[i])
              + w11 * bf2f((unsigned short)c11v[i]);
      vb8[i] = f2bf(v);
    }
    *(v8s*)&ldsB[p * 64 + (j ^ (p & 7)) * 8] = *(const v8s*)vb8;
    __syncthreads();                          // drains vmcnt + lgkm

    // ---- MFMA: 16 per wave per K-step
    __builtin_amdgcn_s_setprio(1);
    #pragma unroll
    for (int ki = 0; ki < 2; ki++) {
      v8s af[4], bfr[2];
      #pragma unroll
      for (int fm = 0; fm < 4; fm++) {
        int row = wm * 64 + fm * 16 + r;
        af[fm] = *(const v8s*)&ldsA[row * 64 + (((ki * 4 + q) ^ (r & 7)) * 8)];
      }
      #pragma unroll
      for (int fn = 0; fn < 2; fn++) {
        int row = wn * 32 + fn * 16 + r;
        bfr[fn] = *(const v8s*)&ldsB[row * 64 + (((ki * 4 + q) ^ (r & 7)) * 8)];
      }
      #pragma unroll
      for (int fm = 0; fm < 4; fm++)
        #pragma unroll
        for (int fn = 0; fn < 2; fn++)
          acc[fm][fn] = __builtin_amdgcn_mfma_f32_16x16x32_bf16(af[fm], bfr[fn], acc[fm][fn], 0, 0, 0);
    }
    __builtin_amdgcn_s_setprio(0);
  }

  // ---- epilogue: atomic accumulate (4 exact addends per element)
  float* op = out + (size_t)b * (256 * 2304) + hw0;
  #pragma unroll
  for (int fm = 0; fm < 4; fm++) {
    int co = wm * 64 + fm * 16 + q * 4;
    #pragma unroll
    for (int fn = 0; fn < 2; fn++) {
      int nn = wn * 32 + fn * 16 + r;
      #pragma unroll
      for (int e = 0; e < 4; e++)
        unsafeAtomicAdd(&op[(size_t)(co + e) * 2304 + nn], acc[fm][fn][e]);
    }
  }
}

extern "C" void kernel_launch(void* const* d_in, const int* in_sizes, int n_in,
                              void* d_out, int out_size, void* d_ws, size_t ws_size,
                              hipStream_t stream) {
  const float* x      = (const float*)d_in[0];
  const float* weight = (const float*)d_in[1];
  const float* off_w  = (const float*)d_in[2];
  const float* off_b  = (const float*)d_in[3];
  const float* mask_w = (const float*)d_in[4];
  const float* mask_b = (const float*)d_in[5];
  float* out = (float*)d_out;
  char* ws = (char*)d_ws;

  unsigned short* xT   = (unsigned short*)(ws);             //  9,437,184 B -> 9,437,184
  unsigned short* wG   = (unsigned short*)(ws + 9437184);   //  1,179,648 B -> 10,616,832
  unsigned short* Wc2  = (unsigned short*)(ws + 10616832);  //    147,456 B -> 10,764,288
  unsigned short* zp   = (unsigned short*)(ws + 10764288);  //        512 B -> 10,764,800
  float*          smp  = (float*)(ws + 10764800);           //  1,990,656 B -> 12,755,456
  float*          parS = (float*)(ws + 12755456);           //  7,077,888 B -> 19,833,344

  hipLaunchKernelGGL(k_zero,   dim3(4608),     dim3(256), 0, stream, out);
  hipLaunchKernelGGL(k_wc,     dim3(288),      dim3(256), 0, stream, off_w, mask_w, Wc2, zp);
  hipLaunchKernelGGL(k_wg,     dim3(256),      dim3(256), 0, stream, weight, wG);
  hipLaunchKernelGGL(k_xt,     dim3(1152),     dim3(256), 0, stream, x, xT);
  hipLaunchKernelGGL(k_cg,     dim3(288, 3),   dim3(256), 0, stream, Wc2, xT, zp, parS);
  hipLaunchKernelGGL(k_fin,    dim3(648),      dim3(256), 0, stream, parS, off_b, mask_b, smp);
  hipLaunchKernelGGL(k_fg,     dim3(1152),     dim3(512), 0, stream, wG, xT, smp, out);
}

// Round 9
// 112.965 us; speedup vs baseline: 1.0784x; 1.0753x over previous
//
#include <hip/hip_runtime.h>
#include <cstdint>
#include <cmath>

#define DEV __device__ __forceinline__

typedef float v4f __attribute__((ext_vector_type(4)));
typedef short v8s __attribute__((ext_vector_type(8)));

// Problem constants
// x: [8,256,48,48] f32; weight: [256,256,3,3]; off_w: [18,256,3,3]; off_b:[18];
// mask_w: [9,256,3,3]; mask_b:[9]; out: [8,256,48,48] f32
static constexpr int HW    = 48 * 48;        // 2304
static constexpr int NPOS  = 8 * HW;         // 18432

DEV float bf2f(unsigned short u) {
  unsigned int v = ((unsigned int)u) << 16;
  float f; __builtin_memcpy(&f, &v, 4); return f;
}
DEV unsigned short f2bf(float f) {
  unsigned int u; __builtin_memcpy(&u, &f, 4);
  unsigned int r = (u + 0x7fffu + ((u >> 16) & 1u)) >> 16;
  return (unsigned short)r;
}

DEV void gload16(const void* g, void* l) {
  __builtin_amdgcn_global_load_lds(
      (const __attribute__((address_space(1))) unsigned int*)g,
      (__attribute__((address_space(3))) unsigned int*)l, 16, 0, 0);
}

// ---------------- prep (fused): zero out; Wc2; zp; wG ------------------------
// grid 4608 x 256. All blocks: zero 16B of out. Blocks 0..287: Wc2 (+zp).
// Blocks 288..543: wG row transpose (block-uniform branch, LDS+sync inside ok).
__global__ __launch_bounds__(256) void k_prep(const float* __restrict__ off_w,
                                              const float* __restrict__ mask_w,
                                              const float* __restrict__ weight,
                                              unsigned short* __restrict__ Wc2,
                                              unsigned short* __restrict__ zp,
                                              unsigned short* __restrict__ wG,
                                              float* __restrict__ out) {
  __shared__ float wrow[2304];
  int bid = blockIdx.x, tid = threadIdx.x;
  int i = bid * 256 + tid;
  ((v4f*)out)[i] = (v4f){0.f, 0.f, 0.f, 0.f};   // 4608*256 = 1,179,648 float4
  if (bid < 288) {
    if (i < 256) zp[i] = 0;
    int o = i / 2304, col = i % 2304;
    int t = col >> 8, c = col & 255;
    float v = 0.f;
    if (o < 18)      v = off_w[(o * 256 + c) * 9 + t];
    else if (o < 27) v = mask_w[((o - 18) * 256 + c) * 9 + t];
    Wc2[i] = f2bf(v);
  } else if (bid < 544) {
    int co = bid - 288;
    const float* wsrc = weight + (size_t)co * 2304;
    for (int k = tid; k < 2304; k += 256) wrow[k] = wsrc[k];
    __syncthreads();
    unsigned short* dst = wG + (size_t)co * 2304;
    #pragma unroll
    for (int k = 0; k < 9; k++)
      dst[k * 256 + tid] = f2bf(wrow[tid * 9 + k]);
  }
}

// ---------------- prep: x NCHW f32 -> xT [b][hw][c] bf16 ---------------------
__global__ void k_xt(const float* __restrict__ x, unsigned short* __restrict__ xT) {
  __shared__ float tile[64][65];
  int bid = blockIdx.x;                 // b*144 + hwt*4 + ct
  int ct = bid & 3; int hwt = (bid >> 2) % 36; int b = bid / 144;
  int c0 = ct * 64, hw0 = hwt * 64;
  int tl = threadIdx.x & 63, tr = threadIdx.x >> 6;
  const float* xb = x + (size_t)(b * 256 + c0) * 2304 + hw0;
  #pragma unroll
  for (int r = 0; r < 16; r++) {
    int cr = tr + r * 4;
    tile[cr][tl] = xb[(size_t)cr * 2304 + tl];
  }
  __syncthreads();
  unsigned short* xo = xT + ((size_t)b * 2304 + hw0) * 256 + c0;
  #pragma unroll
  for (int r = 0; r < 16; r++) {
    int hr = tr + r * 4;
    xo[(size_t)hr * 256 + tl] = f2bf(tile[tl][hr]);
  }
}

// ---------------- offset/mask conv as MFMA GEMM ------------------------------
// S[32][NPOS] = Wc2[32][2304] * im2col(xT)[2304][NPOS], split-K by tap triple.
// grid (288, 3): BN=64, per chunk K=768 (3 taps x 256 ch), BK=64.
// parS layout: [kc][32][NPOS] fp32.
__global__ __launch_bounds__(256) void k_cg(const unsigned short* __restrict__ Wc2,
                                            const unsigned short* __restrict__ xT,
                                            const unsigned short* __restrict__ zp,
                                            float* __restrict__ parS) {
  __shared__ unsigned short ldsA[32 * 64];
  __shared__ unsigned short ldsB[64 * 64];
  int nt = blockIdx.x, kc = blockIdx.y;
  int n0 = nt * 64;
  int b = n0 / 2304, hw0 = n0 % 2304;         // BN=64 divides 2304: one image
  int tid = threadIdx.x, lane = tid & 63, wid = tid >> 6;
  int r = lane & 15, q = lane >> 4;
  int row0 = tid >> 3;                        // staging row (0..31)
  int sslot = (tid & 7) ^ (row0 & 7);         // pre-swizzled 16B slot

  int hwA = hw0 + row0,      hA = hwA / 48, wA = hwA % 48;   // B round 0 row
  int hwB = hw0 + row0 + 32, hB = hwB / 48, wB = hwB % 48;   // B round 1 row

  v4f acc0 = (v4f){0.f, 0.f, 0.f, 0.f};
  v4f acc1 = (v4f){0.f, 0.f, 0.f, 0.f};

  #pragma unroll
  for (int tt = 0; tt < 3; tt++) {
    int t = kc * 3 + tt;
    int dy = kc - 1, dx = tt - 1;
    int yA = hA + dy, xA = wA + dx;
    int yB = hB + dy, xB = wB + dx;
    bool vA = ((unsigned)yA < 48u) && ((unsigned)xA < 48u);
    bool vB = ((unsigned)yB < 48u) && ((unsigned)xB < 48u);
    const unsigned short* baseA2 = Wc2 + (size_t)row0 * 2304 + t * 256 + sslot * 8;
    const unsigned short* base0 = vA ? xT + ((size_t)(b * 2304 + yA * 48 + xA) * 256 + sslot * 8)
                                     : zp + sslot * 8;
    const unsigned short* base1 = vB ? xT + ((size_t)(b * 2304 + yB * 48 + xB) * 256 + sslot * 8)
                                     : zp + sslot * 8;
    #pragma unroll
    for (int cq = 0; cq < 4; cq++) {
      int c0s = cq * 64;
      __syncthreads();                        // prev tile reads done
      gload16(baseA2 + c0s, ldsA + tid * 8);
      gload16(base0  + c0s, ldsB + tid * 8);
      gload16(base1  + c0s, ldsB + 2048 + tid * 8);
      __syncthreads();                        // drain vmcnt + barrier
      #pragma unroll
      for (int ki = 0; ki < 2; ki++) {
        int sl = ((ki * 4 + q) ^ (r & 7)) * 8;
        v8s a0 = *(const v8s*)&ldsA[r * 64 + sl];
        v8s a1 = *(const v8s*)&ldsA[(16 + r) * 64 + sl];
        v8s bb = *(const v8s*)&ldsB[(wid * 16 + r) * 64 + sl];
        acc0 = __builtin_amdgcn_mfma_f32_16x16x32_bf16(a0, bb, acc0, 0, 0, 0);
        acc1 = __builtin_amdgcn_mfma_f32_16x16x32_bf16(a1, bb, acc1, 0, 0, 0);
      }
    }
  }

  float* pp = parS + (size_t)kc * 32 * NPOS + n0;
  #pragma unroll
  for (int e = 0; e < 4; e++) {
    pp[(size_t)(q * 4 + e) * NPOS      + wid * 16 + r] = acc0[e];
    pp[(size_t)(16 + q * 4 + e) * NPOS + wid * 16 + r] = acc1[e];
  }
}

// ---------------- finalize: reduce 3 chunks, bias, sigmoid, coords -----------
// smp layout: [k][pos][{py,px,m}]
__global__ __launch_bounds__(256) void k_fin(const float* __restrict__ parS,
                                             const float* __restrict__ off_b,
                                             const float* __restrict__ mask_b,
                                             float* __restrict__ smp) {
  int k = blockIdx.x / 72;                    // 72 blocks per k (NPOS/256)
  int pos = (blockIdx.x % 72) * 256 + threadIdx.x;
  float s0 = 0.f, s1 = 0.f, s2 = 0.f;
  #pragma unroll
  for (int g = 0; g < 3; g++) {
    const float* pg = parS + (size_t)g * 32 * NPOS + pos;
    s0 += pg[(size_t)(2 * k)     * NPOS];
    s1 += pg[(size_t)(2 * k + 1) * NPOS];
    s2 += pg[(size_t)(18 + k)    * NPOS];
  }
  int hw = pos % 2304; int h = hw / 48, w = hw % 48;
  float m = 1.f / (1.f + expf(-(s2 + mask_b[k])));
  float* sp = smp + ((size_t)k * NPOS + pos) * 3;
  sp[0] = s0 + off_b[2 * k]     + (float)(k / 3) + (float)h - 1.f;
  sp[1] = s1 + off_b[2 * k + 1] + (float)(k % 3) + (float)w - 1.f;
  sp[2] = m;
}

// ---------------- fused deformable-gather + GEMM (small-block TLP) -----------
// C[co][n] += sum_{K-half} wG[co][K] * gather(xT,smp)[K][n]
// BM=128, BN=64, BK=64; 256 threads (2x2 waves); LDS 24KB -> 5-6 blocks/CU.
// Grid 1152 = 8 img x 36 ntl x 2 mt x 2 kc; XCD i owns image i (L2-local).
// 18 K-steps (9 taps x 2 cq); bilinear setup computed once per tap.
// R8 bug fixed: A staging round stride is 2048 ushorts (256 thr x 8), not 4096.
__global__ __launch_bounds__(256, 5) void k_fg(const unsigned short* __restrict__ wG,
                                               const unsigned short* __restrict__ xT,
                                               const float* __restrict__ smp,
                                               float* __restrict__ out) {
  __shared__ unsigned short ldsA[128 * 64];   // 16 KB, [co][k] swizzled slots
  __shared__ unsigned short ldsB[64 * 64];    //  8 KB, [n][k]  swizzled slots
  int raw = blockIdx.x;                       // 1152 = 8 xcd * 144
  int b   = raw & 7;                          // image == XCD
  int idx = raw >> 3;                         // 0..143
  int mt  = idx & 1;
  int kc  = (idx >> 1) & 1;
  int ntl = idx >> 2;                         // 0..35
  int n0 = ntl * 64;                          // hw tile base within image
  int tid = threadIdx.x, lane = tid & 63, wid = tid >> 6;
  int wm = wid & 1, wn = wid >> 1;            // 2 m-waves x 2 n-waves
  int r = lane & 15, q = lane >> 4;
  int p8 = tid >> 3, j = tid & 7;             // gather: 8 threads / position
  int posbase = b * 2304 + n0;
  const unsigned short* xb = xT + (size_t)b * 2304 * 256;
  const unsigned short* wGm = wG + (size_t)mt * 128 * 2304;
  int aslot = j ^ (p8 & 7);                   // staging slot; rows are rd*32+p8,
                                              // (rd*32+p8)&7 == p8&7 for all rd.

  v4f acc[4][2];
  #pragma unroll
  for (int i = 0; i < 4; i++)
    #pragma unroll
    for (int jj = 0; jj < 2; jj++) acc[i][jj] = (v4f){0.f, 0.f, 0.f, 0.f};

  for (int t = 0; t < 9; t++) {
    // ---- bilinear setup once per tap, for both 32-position passes
    float wt[2][4]; int ro[2][4];
    #pragma unroll
    for (int pp = 0; pp < 2; pp++) {
      int p = pp * 32 + p8;
      const float* sp = smp + ((size_t)t * NPOS + posbase + p) * 3;
      float py = sp[0], px = sp[1], m = sp[2];
      float y0f = floorf(py), x0f = floorf(px);
      float wy = py - y0f, wx = px - x0f;
      int y0 = (int)y0f, x0 = (int)x0f;
      bool vy0 = (y0 >= 0) && (y0 <= 47), vy1 = (y0 >= -1) && (y0 <= 46);
      bool vx0 = (x0 >= 0) && (x0 <= 47), vx1 = (x0 >= -1) && (x0 <= 46);
      int yc0 = min(max(y0, 0), 47), yc1 = min(max(y0 + 1, 0), 47);
      int xc0 = min(max(x0, 0), 47), xc1 = min(max(x0 + 1, 0), 47);
      wt[pp][0] = (1.f - wy) * (1.f - wx) * m * (float)(vy0 && vx0);
      wt[pp][1] = (1.f - wy) * wx         * m * (float)(vy0 && vx1);
      wt[pp][2] = wy         * (1.f - wx) * m * (float)(vy1 && vx0);
      wt[pp][3] = wy         * wx         * m * (float)(vy1 && vx1);
      ro[pp][0] = yc0 * 48 + xc0; ro[pp][1] = yc0 * 48 + xc1;
      ro[pp][2] = yc1 * 48 + xc0; ro[pp][3] = yc1 * 48 + xc1;
    }
    #pragma unroll
    for (int cq = 0; cq < 2; cq++) {
      int cc0 = kc * 128 + cq * 64;           // 64-channel slice base
      int cb = cc0 + j * 8;
      __syncthreads();                        // prev step's LDS reads done
      // ---- stage A: 128x64 via global_load_lds, pre-swizzled source
      #pragma unroll
      for (int rd = 0; rd < 4; rd++)
        gload16(wGm + (size_t)(rd * 32 + p8) * 2304 + t * 256 + cc0 + aslot * 8,
                ldsA + rd * 2048 + tid * 8);
      // ---- gather B tile: 2 passes x 32 pos x 64 ch, swizzled ds_write
      #pragma unroll
      for (int pp = 0; pp < 2; pp++) {
        int p = pp * 32 + p8;
        v8s c00 = *(const v8s*)&xb[ro[pp][0] * 256 + cb];
        v8s c01 = *(const v8s*)&xb[ro[pp][1] * 256 + cb];
        v8s c10 = *(const v8s*)&xb[ro[pp][2] * 256 + cb];
        v8s c11 = *(const v8s*)&xb[ro[pp][3] * 256 + cb];
        unsigned short vb8[8];
        #pragma unroll
        for (int i = 0; i < 8; i++) {
          float v = wt[pp][0] * bf2f((unsigned short)c00[i])
                  + wt[pp][1] * bf2f((unsigned short)c01[i])
                  + wt[pp][2] * bf2f((unsigned short)c10[i])
                  + wt[pp][3] * bf2f((unsigned short)c11[i]);
          vb8[i] = f2bf(v);
        }
        *(v8s*)&ldsB[p * 64 + (j ^ (p & 7)) * 8] = *(const v8s*)vb8;
      }
      __syncthreads();                        // drains vmcnt + lgkm

      // ---- MFMA: 16 per wave per K-step
      #pragma unroll
      for (int ki = 0; ki < 2; ki++) {
        v8s af[4], bfr[2];
        #pragma unroll
        for (int fm = 0; fm < 4; fm++) {
          int row = wm * 64 + fm * 16 + r;
          af[fm] = *(const v8s*)&ldsA[row * 64 + (((ki * 4 + q) ^ (r & 7)) * 8)];
        }
        #pragma unroll
        for (int fn = 0; fn < 2; fn++) {
          int row = wn * 32 + fn * 16 + r;
          bfr[fn] = *(const v8s*)&ldsB[row * 64 + (((ki * 4 + q) ^ (r & 7)) * 8)];
        }
        #pragma unroll
        for (int fm = 0; fm < 4; fm++)
          #pragma unroll
          for (int fn = 0; fn < 2; fn++)
            acc[fm][fn] = __builtin_amdgcn_mfma_f32_16x16x32_bf16(af[fm], bfr[fn], acc[fm][fn], 0, 0, 0);
      }
    }
  }

  // ---- epilogue: atomic accumulate (2 exact addends per element)
  float* op = out + (size_t)b * (256 * 2304) + n0;
  #pragma unroll
  for (int fm = 0; fm < 4; fm++) {
    int co = mt * 128 + wm * 64 + fm * 16 + q * 4;
    #pragma unroll
    for (int fn = 0; fn < 2; fn++) {
      int nn = wn * 32 + fn * 16 + r;
      #pragma unroll
      for (int e = 0; e < 4; e++)
        unsafeAtomicAdd(&op[(size_t)(co + e) * 2304 + nn], acc[fm][fn][e]);
    }
  }
}

extern "C" void kernel_launch(void* const* d_in, const int* in_sizes, int n_in,
                              void* d_out, int out_size, void* d_ws, size_t ws_size,
                              hipStream_t stream) {
  const float* x      = (const float*)d_in[0];
  const float* weight = (const float*)d_in[1];
  const float* off_w  = (const float*)d_in[2];
  const float* off_b  = (const float*)d_in[3];
  const float* mask_w = (const float*)d_in[4];
  const float* mask_b = (const float*)d_in[5];
  float* out = (float*)d_out;
  char* ws = (char*)d_ws;

  unsigned short* xT   = (unsigned short*)(ws);             //  9,437,184 B -> 9,437,184
  unsigned short* wG   = (unsigned short*)(ws + 9437184);   //  1,179,648 B -> 10,616,832
  unsigned short* Wc2  = (unsigned short*)(ws + 10616832);  //    147,456 B -> 10,764,288
  unsigned short* zp   = (unsigned short*)(ws + 10764288);  //        512 B -> 10,764,800
  float*          smp  = (float*)(ws + 10764800);           //  1,990,656 B -> 12,755,456
  float*          parS = (float*)(ws + 12755456);           //  7,077,888 B -> 19,833,344

  hipLaunchKernelGGL(k_prep,   dim3(4608),     dim3(256), 0, stream,
                     off_w, mask_w, weight, Wc2, zp, wG, out);
  hipLaunchKernelGGL(k_xt,     dim3(1152),     dim3(256), 0, stream, x, xT);
  hipLaunchKernelGGL(k_cg,     dim3(288, 3),   dim3(256), 0, stream, Wc2, xT, zp, parS);
  hipLaunchKernelGGL(k_fin,    dim3(648),      dim3(256), 0, stream, parS, off_b, mask_b, smp);
  hipLaunchKernelGGL(k_fg,     dim3(1152),     dim3(256), 0, stream, wG, xT, smp, out);
}